// Round 1
// baseline (2105.089 us; speedup 1.0000x reference)
//
#include <hip/hip_runtime.h>

#define CIN   32
#define COUTC 32
#define HH    64
#define WWID  64
#define TPB   128

// DPP-based add of rotated value (row = 16 lanes)
template <int CTRL>
__device__ __forceinline__ float dpp_add(float v) {
  int t = __builtin_amdgcn_update_dpp(0, __float_as_int(v), CTRL, 0xF, 0xF, true);
  return v + __int_as_float(t);
}

// sum over the 32-lane half-wave (lanes 0-31 and 32-63 reduced independently)
__device__ __forceinline__ float reduce32(float v) {
  v = dpp_add<0x128>(v);  // row_ror:8
  v = dpp_add<0x124>(v);  // row_ror:4
  v = dpp_add<0x122>(v);  // row_ror:2
  v = dpp_add<0x121>(v);  // row_ror:1  -> each 16-lane row holds row-sum
  int t = __builtin_amdgcn_ds_swizzle(__float_as_int(v), 0x401F); // lane ^ 16
  return v + __int_as_float(t);
}

__global__ __launch_bounds__(TPB, 2) void dppc_kernel(
    const float* __restrict__ x, const float* __restrict__ Wp,
    const float* __restrict__ bp, float* __restrict__ out) {
  // Wp slice for current cout: 288 rows x 32 cols, row stride 36 (16B aligned, spread banks)
  __shared__ float wlds[288 * 36];
  // padded x tile: [r 0..2][cc 0..17][c 0..31]  (rows h-1..h+1, cols w0-1..w0+16)
  __shared__ float xs2[3 * 18 * 32];
  // bias-predictor rows (Wp rows 9216..9247): [o][c]
  __shared__ float wb[32 * 32];

  const int tid = threadIdx.x;
  const int cin = tid & 31;
  const int pg  = tid >> 5;          // 0..3

  const int bid = blockIdx.x;
  const int b   = bid >> 8;          // 0..1
  const int t   = bid & 255;
  const int h   = t >> 2;            // 0..63
  const int w0  = (t & 3) << 4;      // 0,16,32,48

  // ---- stage xs2 (zero-padded halo) ----
  for (int idx = tid; idx < 3 * 18 * 32; idx += TPB) {
    int c  = idx & 31;
    int rc = idx >> 5;               // 0..53
    int r  = rc / 18;
    int cc = rc - r * 18;
    int hh = h - 1 + r;
    int ww = w0 - 1 + cc;
    float v = 0.f;
    if ((unsigned)hh < HH && (unsigned)ww < WWID)
      v = x[((b * CIN + c) * HH + hh) * WWID + ww];
    xs2[idx] = v;
  }
  // ---- stage wb ----
  for (int idx = tid; idx < 32 * 32; idx += TPB)
    wb[idx] = Wp[9216 * 32 + idx];
  __syncthreads();

  // ---- per-thread x fragments (pixels p = pg + 4*j) ----
  float4 xr[4][8];     // full x column for each of my 4 pixels
  float  patch[4][9];  // my cin's 3x3 patch for each pixel
  float  x_own[4];     // x[cin] at my pixels (for fused dyn_b)
  #pragma unroll
  for (int j = 0; j < 4; ++j) {
    int p = pg + 4 * j;
    const float4* src = reinterpret_cast<const float4*>(&xs2[(18 + 1 + p) * 32]);
    #pragma unroll
    for (int c4 = 0; c4 < 8; ++c4) xr[j][c4] = src[c4];
    #pragma unroll
    for (int kh = 0; kh < 3; ++kh)
      #pragma unroll
      for (int kw = 0; kw < 3; ++kw)
        patch[j][kh * 3 + kw] = xs2[(kh * 18 + p + kw) * 32 + cin];
    x_own[j] = xs2[(18 + 1 + p) * 32 + cin];
  }

  float* outb = out + ((b * COUTC) * HH + h) * WWID + w0;

  #pragma unroll 1
  for (int o = 0; o < COUTC; ++o) {
    __syncthreads();  // previous iteration's wlds reads complete
    {
      const float4* wp4 = reinterpret_cast<const float4*>(Wp + o * 288 * 32);
      #pragma unroll
      for (int i = 0; i < 18; ++i) {
        int f4 = tid + i * TPB;              // 0..2303
        float4 v = wp4[f4];
        int r = f4 >> 3, c4 = f4 & 7;
        *reinterpret_cast<float4*>(&wlds[r * 36 + c4 * 4]) = v;
      }
    }
    __syncthreads();  // wlds visible

    float bprow[9];
    const float* bpo = bp + (o * 32 + cin) * 9;
    #pragma unroll
    for (int k = 0; k < 9; ++k) bprow[k] = bpo[k];
    float bpt = bp[9216 + o];

    // pred dot: w[j][k] = bp + Wp[(o,cin,k),:] . x[:, pixel_j]
    float w[4][9];
    #pragma unroll
    for (int j = 0; j < 4; ++j)
      #pragma unroll
      for (int k = 0; k < 9; ++k) w[j][k] = bprow[k];

    #pragma unroll
    for (int k = 0; k < 9; ++k) {
      const float4* row = reinterpret_cast<const float4*>(&wlds[(cin * 9 + k) * 36]);
      #pragma unroll
      for (int c4 = 0; c4 < 8; ++c4) {
        float4 wp = row[c4];
        #pragma unroll
        for (int j = 0; j < 4; ++j) {
          w[j][k] += wp.x * xr[j][c4].x + wp.y * xr[j][c4].y
                   + wp.z * xr[j][c4].z + wp.w * xr[j][c4].w;
        }
      }
    }

    float wbv = wb[o * 32 + cin];
    #pragma unroll
    for (int j = 0; j < 4; ++j) {
      // L2 norm over cin (cross-lane), per k
      #pragma unroll
      for (int k = 0; k < 9; ++k) {
        float s = reduce32(w[j][k] * w[j][k]);
        w[j][k] *= rsqrtf(fmaxf(s, 1e-24f));
      }
      // L2 norm over k (thread-local)
      float ss = 0.f;
      #pragma unroll
      for (int k = 0; k < 9; ++k) ss += w[j][k] * w[j][k];
      float rn2 = rsqrtf(fmaxf(ss, 1e-24f));
      // contraction + fused dyn_b partial (summed over cin by reduce32)
      float pv = wbv * x_own[j];
      #pragma unroll
      for (int k = 0; k < 9; ++k) pv += (w[j][k] * rn2) * patch[j][k];
      float tot = reduce32(pv);
      if (cin == 0) outb[o * HH * WWID + pg + 4 * j] = tot + bpt;
    }
  }
}

extern "C" void kernel_launch(void* const* d_in, const int* in_sizes, int n_in,
                              void* d_out, int out_size, void* d_ws, size_t ws_size,
                              hipStream_t stream) {
  const float* x  = (const float*)d_in[0];
  const float* Wp = (const float*)d_in[1];
  const float* bp = (const float*)d_in[2];
  float* out = (float*)d_out;
  dppc_kernel<<<512, TPB, 0, stream>>>(x, Wp, bp, out);
}

// Round 2
// 136.590 us; speedup vs baseline: 15.4118x; 15.4118x over previous
//
#include <hip/hip_runtime.h>

#define TPB 256

typedef __attribute__((ext_vector_type(8))) short short8;
typedef __attribute__((ext_vector_type(4))) float f32x4;

// pack two fp32 -> two bf16 in one u32 (round-half-up)
__device__ __forceinline__ unsigned f2bf_pk(float a, float b) {
  unsigned ua = (__float_as_uint(a) + 0x8000u) >> 16;
  unsigned ub = (__float_as_uint(b) + 0x8000u) & 0xffff0000u;
  return ua | ub;
}
__device__ __forceinline__ float bflo(unsigned v) { return __uint_as_float(v << 16); }
__device__ __forceinline__ float bfhi(unsigned v) { return __uint_as_float(v & 0xffff0000u); }

// Block: 64 px (one image row) x 8 couts. Grid = 2*64 row-tiles * 4 o-groups = 512.
// Phase 1: pred = Wp_o @ x  via mfma_f32_16x16x32_bf16 (K=32 in one step) -> LDS (bf16 row-pairs)
// Phase 2: thread=px (x4 c-quarters): ss_k partials -> LDS combine -> normalize+contract.
__global__ __launch_bounds__(TPB, 2) void dppc2_kernel(
    const float* __restrict__ x, const float* __restrict__ Wp,
    const float* __restrict__ bp, float* __restrict__ out) {
  // LDS: 13056 + 5120 + 38016 + 9216 + 32 + 1024 + 9216 + 1024 = 76704 B -> 2 blocks/CU
  __shared__ __align__(16) unsigned short xrow[3 * 32 * 68];  // [r][c][w+2], bf16, zero-padded
  __shared__ __align__(16) unsigned short xT[64 * 40];        // [px][c] bf16 (B-frag source)
  __shared__ __align__(16) unsigned predb[144 * 66];          // row-pairs x px, packed bf16x2
  __shared__ float bp_s[8 * 288];
  __shared__ float bias8[8];
  __shared__ float Wb_s[8 * 32];
  __shared__ float ssp[4 * 9 * 64];
  __shared__ float outp[4 * 64];

  const int tid = threadIdx.x;
  const int bid = blockIdx.x;
  const int og = bid & 3;        // o-group: couts og*8 .. og*8+7
  const int t  = bid >> 2;
  const int b  = t >> 6;
  const int h  = t & 63;

  // ---- phase 0a: zero xrow ----
  unsigned* xz = (unsigned*)xrow;  // 3264 words
  for (int i = tid; i < 3264; i += TPB) xz[i] = 0;
  __syncthreads();

  // ---- phase 0b: fill xrow (rows h-1..h+1, bf16), bp_s, Wb_s, bias8 ----
  for (int i = tid; i < 1536; i += TPB) {  // 1536 float4 = 3*32*64 floats
    int r = i >> 9, c = (i >> 4) & 31, w4 = i & 15;
    int hh = h - 1 + r;
    if ((unsigned)hh < 64u) {
      const float4 v = *(const float4*)(x + (((b * 32 + c) * 64 + hh) * 64 + w4 * 4));
      unsigned* dst = (unsigned*)&xrow[(r * 32 + c) * 68 + 2 + w4 * 4];
      dst[0] = f2bf_pk(v.x, v.y);
      dst[1] = f2bf_pk(v.z, v.w);
    }
  }
  for (int i = tid; i < 2304; i += TPB) bp_s[i] = bp[og * 2304 + i];
  Wb_s[tid & 255] = Wp[(9216 + og * 8 + (tid >> 5)) * 32 + (tid & 31)];
  if (tid < 8) bias8[tid] = bp[9216 + og * 8 + tid];
  __syncthreads();

  // ---- phase 0c: xT[px][c] from center row; patch regs (packed bf16 pairs) ----
  for (int i = tid; i < 2048; i += TPB) {
    int px_ = i & 63, c_ = i >> 6;
    xT[px_ * 40 + c_] = xrow[(32 + c_) * 68 + 2 + px_];
  }
  const int px = tid & 63;   // phase-2 pixel
  const int q  = tid >> 6;   // c-quarter (== wave id)
  unsigned patchp[36];
#pragma unroll
  for (int i = 0; i < 36; ++i) patchp[i] = 0;
#pragma unroll
  for (int c8 = 0; c8 < 8; ++c8) {
#pragma unroll
    for (int k = 0; k < 9; ++k) {
      const int kh = k / 3, kw = k - kh * 3;
      unsigned v = (unsigned)xrow[(kh * 32 + (q * 8 + c8)) * 68 + 1 + kw + px];
      const int idx = c8 * 9 + k;
      patchp[idx >> 1] |= (idx & 1) ? (v << 16) : v;
    }
  }
  __syncthreads();

  // ---- persistent B fragment: B[k=c][n=px], lane: n=lane&15 (+16*wave), k=(lane>>4)*8+j
  const int lane = tid & 63;
  const int wv   = tid >> 6;
  const int m16  = lane & 15, kq = lane >> 4;
  const short8 bfrag = *(const short8*)&xT[(wv * 16 + m16) * 40 + kq * 8];
  const f32x4 zacc = {0.f, 0.f, 0.f, 0.f};
  const int pxm = wv * 16 + m16;

  for (int oo = 0; oo < 8; ++oo) {
    const int o = og * 8 + oo;
    __syncthreads();  // predb/outp safe to overwrite

    // ---- phase 1: pred tile 288x64 via 18 row-tile MFMAs per wave ----
    const float* Abase = Wp + (o * 288 + m16) * 32 + kq * 8;
#pragma unroll 3
    for (int rt = 0; rt < 18; ++rt) {
      const float* ap = Abase + rt * 16 * 32;
      float4 a0 = *(const float4*)ap;
      float4 a1 = *(const float4*)(ap + 4);
      union { short8 v; unsigned u[4]; } af;
      af.u[0] = f2bf_pk(a0.x, a0.y);
      af.u[1] = f2bf_pk(a0.z, a0.w);
      af.u[2] = f2bf_pk(a1.x, a1.y);
      af.u[3] = f2bf_pk(a1.z, a1.w);
      f32x4 acc = __builtin_amdgcn_mfma_f32_16x16x32_bf16(af.v, bfrag, zacc, 0, 0, 0);
      const int r0 = rt * 16 + kq * 4;  // 4 consecutive rows, mult of 4
      const float* bpr = bp_s + oo * 288 + r0;
      float p0 = acc[0] + bpr[0];
      float p1 = acc[1] + bpr[1];
      float p2 = acc[2] + bpr[2];
      float p3 = acc[3] + bpr[3];
      unsigned* dst = &predb[(r0 >> 1) * 66 + pxm];
      dst[0]  = f2bf_pk(p0, p1);
      dst[66] = f2bf_pk(p2, p3);
    }
    __syncthreads();

    // ---- pass A: ss_k partial over this thread's 8 cin ----
    float ss[9];
#pragma unroll
    for (int k = 0; k < 9; ++k) ss[k] = 0.f;
#pragma unroll
    for (int c8 = 0; c8 < 8; ++c8) {
      const int r0 = (q * 8 + c8) * 9;
      const unsigned* src = &predb[(r0 >> 1) * 66 + px];
      unsigned wds[5];
#pragma unroll
      for (int j = 0; j < 5; ++j) wds[j] = src[j * 66];
#pragma unroll
      for (int k = 0; k < 9; ++k) {
        const int pos = k + (c8 & 1);  // r0 parity == c8 parity (q*8 even)
        float p = (pos & 1) ? bfhi(wds[pos >> 1]) : bflo(wds[pos >> 1]);
        ss[k] += p * p;
      }
    }
#pragma unroll
    for (int k = 0; k < 9; ++k) ssp[(q * 9 + k) * 64 + px] = ss[k];
    __syncthreads();

    // ---- combine ss, pass B: normalize + contract + dyn bias ----
    float rinv[9];
#pragma unroll
    for (int k = 0; k < 9; ++k) {
      float s = ssp[k * 64 + px] + ssp[(9 + k) * 64 + px] +
                ssp[(18 + k) * 64 + px] + ssp[(27 + k) * 64 + px];
      rinv[k] = rsqrtf(fmaxf(s, 1e-24f));  // == 1/max(sqrt(s),1e-12)
    }
    float oacc = 0.f;
#pragma unroll
    for (int c8 = 0; c8 < 8; ++c8) {
      const int r0 = (q * 8 + c8) * 9;
      const unsigned* src = &predb[(r0 >> 1) * 66 + px];
      unsigned wds[5];
#pragma unroll
      for (int j = 0; j < 5; ++j) wds[j] = src[j * 66];
      float tk[9];
      float s2 = 0.f;
#pragma unroll
      for (int k = 0; k < 9; ++k) {
        const int pos = k + (c8 & 1);
        float p = (pos & 1) ? bfhi(wds[pos >> 1]) : bflo(wds[pos >> 1]);
        float tv = p * rinv[k];
        tk[k] = tv;
        s2 += tv * tv;
      }
      float r2 = rsqrtf(fmaxf(s2, 1e-24f));
      float dot = 0.f;
#pragma unroll
      for (int k = 0; k < 9; ++k) {
        const int idx = c8 * 9 + k;
        float pv = (idx & 1) ? bfhi(patchp[idx >> 1]) : bflo(patchp[idx >> 1]);
        dot += tk[k] * pv;
      }
      oacc += r2 * dot;
      // dyn bias partial: Wb[o][c] * x[c, px]  (center patch element k=4)
      const int idc = c8 * 9 + 4;
      float xc = (idc & 1) ? bfhi(patchp[idc >> 1]) : bflo(patchp[idc >> 1]);
      oacc += Wb_s[oo * 32 + (q * 8 + c8)] * xc;
    }
    outp[q * 64 + px] = oacc;
    __syncthreads();

    if (tid < 64) {
      float r = outp[tid] + outp[64 + tid] + outp[128 + tid] + outp[192 + tid] + bias8[oo];
      out[((b * 32 + o) * 64 + h) * 64 + tid] = r;
    }
  }
}

extern "C" void kernel_launch(void* const* d_in, const int* in_sizes, int n_in,
                              void* d_out, int out_size, void* d_ws, size_t ws_size,
                              hipStream_t stream) {
  const float* x  = (const float*)d_in[0];
  const float* Wp = (const float*)d_in[1];
  const float* bp = (const float*)d_in[2];
  float* out = (float*)d_out;
  dppc2_kernel<<<512, TPB, 0, stream>>>(x, Wp, bp, out);
}

// Round 3
// 85.830 us; speedup vs baseline: 24.5263x; 1.5914x over previous
//
#include <hip/hip_runtime.h>

#define TPB 256

typedef __attribute__((ext_vector_type(8))) short short8;
typedef __attribute__((ext_vector_type(4))) float f32x4;

__device__ __forceinline__ unsigned f2bf_pk(float a, float b) {
  return ((__float_as_uint(a) + 0x8000u) >> 16) | ((__float_as_uint(b) + 0x8000u) & 0xffff0000u);
}
__device__ __forceinline__ float bf2f(unsigned short v) {
  return __uint_as_float(((unsigned)v) << 16);
}

// ---- prep: permuted bf16 A-fragment table -------------------------------
// Wq u32[idx], idx = (((o*18+rt)*64+lane)*8 + j)/2
// value pair = bf16(Wp[(o*288 + (m16>>2)*72 + rt*4 + (m16&3))*32 + (lane>>4)*8 + 2*j2 (+1)])
__global__ void prep_kernel(const float* __restrict__ Wp, unsigned* __restrict__ Wq) {
  int idx = blockIdx.x * blockDim.x + threadIdx.x;  // 147456 u32
  if (idx >= 32 * 18 * 64 * 4) return;
  int j2   = idx & 3;
  int lane = (idx >> 2) & 63;
  int rt   = (idx >> 8) % 18;
  int o    = (idx >> 8) / 18;
  int m16 = lane & 15, kq = lane >> 4;
  int row = o * 288 + (m16 >> 2) * 72 + rt * 4 + (m16 & 3);
  const float* src = Wp + row * 32 + kq * 8 + j2 * 2;
  Wq[idx] = f2bf_pk(src[0], src[1]);
}

// ---- main: block = 64 px (one row) x 4 couts; syncless o-loop -----------
template <bool USE_WQ>
__global__ __launch_bounds__(TPB, 2) void dppc3_kernel(
    const float* __restrict__ x, const float* __restrict__ Wp,
    const float* __restrict__ bp, const unsigned* __restrict__ Wq,
    float* __restrict__ out) {
  __shared__ __align__(16) unsigned short xrow[3 * 32 * 68];  // [r][c][w pad], bf16
  __shared__ __align__(16) float bp_s[4 * 288];
  __shared__ float Wb_s[4 * 32];
  __shared__ float bias4[4];

  const int tid = threadIdx.x;
  const int bid = blockIdx.x;
  const int og  = bid & 7;      // couts og*4 .. og*4+3
  const int t   = bid >> 3;
  const int b   = t >> 6;
  const int h   = t & 63;

  // stage: zero xrow, fill 3 rows of x as bf16, bp slice, Wb slice, biases
  unsigned* xz = (unsigned*)xrow;  // 3264 words
  for (int i = tid; i < 3264; i += TPB) xz[i] = 0;
  __syncthreads();
  for (int i = tid; i < 1536; i += TPB) {  // 3*32*16 float4
    int r = i >> 9, c = (i >> 4) & 31, w4 = i & 15;
    int hh = h - 1 + r;
    if ((unsigned)hh < 64u) {
      const float4 v = *(const float4*)(x + (((b * 32 + c) * 64 + hh) * 64 + w4 * 4));
      unsigned* dst = (unsigned*)&xrow[(r * 32 + c) * 68 + 2 + w4 * 4];
      dst[0] = f2bf_pk(v.x, v.y);
      dst[1] = f2bf_pk(v.z, v.w);
    }
  }
  for (int i = tid; i < 1152; i += TPB) bp_s[i] = bp[og * 1152 + i];
  if (tid < 128) Wb_s[tid] = Wp[(9216 + og * 4 + (tid >> 5)) * 32 + (tid & 31)];
  if (tid < 4) bias4[tid] = bp[9216 + og * 4 + tid];
  __syncthreads();

  const int lane = tid & 63;
  const int wv   = tid >> 6;
  const int m16  = lane & 15, kq = lane >> 4;
  const int px   = wv * 16 + m16;

  // persistent B fragment: B[k=cin=kq*8+j][n=px=m16]
  union { short8 v; unsigned short s[8]; } bf_;
#pragma unroll
  for (int j = 0; j < 8; ++j)
    bf_.s[j] = xrow[(32 + kq * 8 + j) * 68 + 2 + px];
  const short8 bfrag = bf_.v;
  const f32x4 zacc = {0.f, 0.f, 0.f, 0.f};

  // patch (fp32): my 8 cins (kq*8+c8) x 9 taps at my px
  float patch[72];
#pragma unroll
  for (int c8 = 0; c8 < 8; ++c8)
#pragma unroll
    for (int kk = 0; kk < 9; ++kk) {
      const int kh = kk / 3, kw = kk - kh * 3;
      patch[c8 * 9 + kk] = bf2f(xrow[(kh * 32 + kq * 8 + c8) * 68 + 1 + kw + px]);
    }

#pragma unroll 1
  for (int oo = 0; oo < 4; ++oo) {
    const int o = og * 4 + oo;

    // phase 1: 18 MFMAs; lane ends up holding pred fp32 for idx = c8*9+k
    // (c = kq*8+c8) at pixel px:  acc[idx>>2][idx&3]
    f32x4 acc[18];
    if (USE_WQ) {
      const short8* wq = (const short8*)Wq + (o * 18) * 64 + lane;
#pragma unroll
      for (int rt = 0; rt < 18; ++rt)
        acc[rt] = __builtin_amdgcn_mfma_f32_16x16x32_bf16(wq[rt * 64], bfrag, zacc, 0, 0, 0);
    } else {
      const float* ab = Wp + (o * 288 + (m16 >> 2) * 72 + (m16 & 3)) * 32 + kq * 8;
#pragma unroll
      for (int rt = 0; rt < 18; ++rt) {
        const float* ap = ab + rt * 4 * 32;
        float4 a0 = *(const float4*)ap;
        float4 a1 = *(const float4*)(ap + 4);
        union { short8 v; unsigned u[4]; } af;
        af.u[0] = f2bf_pk(a0.x, a0.y);
        af.u[1] = f2bf_pk(a0.z, a0.w);
        af.u[2] = f2bf_pk(a1.x, a1.y);
        af.u[3] = f2bf_pk(a1.z, a1.w);
        acc[rt] = __builtin_amdgcn_mfma_f32_16x16x32_bf16(af.v, bfrag, zacc, 0, 0, 0);
      }
    }
    // + predictor bias (broadcast LDS reads)
#pragma unroll
    for (int rt = 0; rt < 18; ++rt) {
      const f32x4 bb = *(const f32x4*)&bp_s[oo * 288 + kq * 72 + rt * 4];
      acc[rt] += bb;
    }

    // cin-norm denominators: local partial + butterfly over kq groups
    float ss[9];
#pragma unroll
    for (int kk = 0; kk < 9; ++kk) ss[kk] = 0.f;
#pragma unroll
    for (int c8 = 0; c8 < 8; ++c8)
#pragma unroll
      for (int kk = 0; kk < 9; ++kk) {
        const int idx = c8 * 9 + kk;
        const float v = acc[idx >> 2][idx & 3];
        ss[kk] += v * v;
      }
#pragma unroll
    for (int kk = 0; kk < 9; ++kk) {
      float s = ss[kk];
      s += __shfl_xor(s, 16);
      s += __shfl_xor(s, 32);
      ss[kk] = rsqrtf(fmaxf(s, 1e-24f));  // == 1/max(sqrt(s),1e-12)
    }

    // k-norm + contraction + dyn-bias partial (all local), then butterfly
    float oacc = 0.f;
#pragma unroll
    for (int c8 = 0; c8 < 8; ++c8) {
      float tk[9];
      float s2 = 0.f;
#pragma unroll
      for (int kk = 0; kk < 9; ++kk) {
        const int idx = c8 * 9 + kk;
        const float tv = acc[idx >> 2][idx & 3] * ss[kk];
        tk[kk] = tv;
        s2 += tv * tv;
      }
      const float r2 = rsqrtf(fmaxf(s2, 1e-24f));
      float dot = 0.f;
#pragma unroll
      for (int kk = 0; kk < 9; ++kk) dot += tk[kk] * patch[c8 * 9 + kk];
      oacc += r2 * dot;
      oacc += Wb_s[oo * 32 + kq * 8 + c8] * patch[c8 * 9 + 4];  // dyn bias partial
    }
    oacc += __shfl_xor(oacc, 16);
    oacc += __shfl_xor(oacc, 32);
    if (kq == 0)
      out[((b * 32 + o) * 64 + h) * 64 + px] = oacc + bias4[oo];
  }
}

extern "C" void kernel_launch(void* const* d_in, const int* in_sizes, int n_in,
                              void* d_out, int out_size, void* d_ws, size_t ws_size,
                              hipStream_t stream) {
  const float* x  = (const float*)d_in[0];
  const float* Wp = (const float*)d_in[1];
  const float* bp = (const float*)d_in[2];
  float* out = (float*)d_out;
  const size_t wq_bytes = (size_t)32 * 18 * 64 * 8 * 2;  // 589824
  if (ws_size >= wq_bytes) {
    prep_kernel<<<576, 256, 0, stream>>>(Wp, (unsigned*)d_ws);
    dppc3_kernel<true><<<1024, TPB, 0, stream>>>(x, Wp, bp, (const unsigned*)d_ws, out);
  } else {
    dppc3_kernel<false><<<1024, TPB, 0, stream>>>(x, Wp, bp, nullptr, out);
  }
}